// Round 1
// baseline (378.323 us; speedup 1.0000x reference)
//
#include <hip/hip_runtime.h>
#include <math.h>

// Problem constants
#define Bn 32
#define Sn 16384
#define Kn 64
#define Nn 128

#define P1  8    // pass-1 sample-chunks per (b,view)
#define NSB 32   // pass-2 blocks per batch

// workspace layout in floats
#define WS_CSPART 0                         // B*2*P1*64
#define WS_CS     (Bn*2*P1*64)              // B*2*64
#define WS_GRAM   (WS_CS + Bn*2*64)         // B*3*4096 (Gii, Gij, Gjj per batch)
#define WS_LOSS   (WS_GRAM + Bn*3*4096)     // B

// ---------------- Pass 1: column sums (deterministic two-stage) ----------------
__global__ __launch_bounds__(256) void k_colsum(const float* __restrict__ qi,
                                                const float* __restrict__ qj,
                                                float* __restrict__ ws) {
    const int blk   = blockIdx.x;       // 0 .. B*2*P1-1
    const int chunk = blk % P1;
    const int pair  = blk / P1;         // b*2 + v
    const int v = pair & 1, b = pair >> 1;
    const float* __restrict__ src = v ? qj : qi;
    const int tid = threadIdx.x;
    const int c4 = (tid & 15) * 4;      // column base (4 cols per lane)
    const int sg = tid >> 4;            // 0..15 sample-group
    const long base = (long)b * Sn * Kn + (long)chunk * (Sn / P1) * Kn;

    float4 acc = make_float4(0.f, 0.f, 0.f, 0.f);
    for (int s = sg; s < Sn / P1; s += 16) {
        const float4 q = *(const float4*)(src + base + (long)s * Kn + c4);
        acc.x += q.x; acc.y += q.y; acc.z += q.z; acc.w += q.w;
    }
    __shared__ float red[16 * 64];
    *(float4*)&red[sg * 64 + c4] = acc;
    __syncthreads();
    if (tid < 64) {
        float s = 0.f;
        #pragma unroll
        for (int g = 0; g < 16; ++g) s += red[g * 64 + tid];
        ws[WS_CSPART + (pair * P1 + chunk) * 64 + tid] = s;
    }
}

__global__ void k_colsum_reduce(float* __restrict__ ws) {
    const int pair = blockIdx.x;   // B*2 blocks, 64 threads
    const int tid = threadIdx.x;
    float s = 0.f;
    #pragma unroll
    for (int p = 0; p < P1; ++p) s += ws[WS_CSPART + (pair * P1 + p) * 64 + tid];
    ws[WS_CS + pair * 64 + tid] = s;
}

// ---------------- Pass 2: normalize + 3x 64x64 Gram accumulation ----------------
__global__ __launch_bounds__(256) void k_gram(const float* __restrict__ qi,
                                              const float* __restrict__ qj,
                                              float* __restrict__ ws) {
    const int b  = blockIdx.x / NSB;
    const int sb = blockIdx.x % NSB;
    const int tid = threadIdx.x;
    const int w = tid >> 6, l = tid & 63;
    const int c4 = (l & 15) * 4;         // staging column base

    // per-lane inverse column sums for the 4 staged columns
    const float4 csi = *(const float4*)&ws[WS_CS + (b * 2 + 0) * 64 + c4];
    const float4 csj = *(const float4*)&ws[WS_CS + (b * 2 + 1) * 64 + c4];
    const float4 ici = make_float4(1.f / csi.x, 1.f / csi.y, 1.f / csi.z, 1.f / csi.w);
    const float4 icj = make_float4(1.f / csj.x, 1.f / csj.y, 1.f / csj.z, 1.f / csj.w);

    const long bb = (long)b * Sn * Kn;
    __shared__ float lpi[32 * 64];
    __shared__ float lpj[32 * 64];

    const int r0 = (tid >> 4) * 4;       // gram tile row base
    const int c0 = (tid & 15) * 4;       // gram tile col base

    float aii[4][4] = {{0}}, aij[4][4] = {{0}}, ajj[4][4] = {{0}};

    const int s_start = sb * (Sn / NSB);
    const int nchunk = (Sn / NSB) / 32;

    for (int ct = 0; ct < nchunk; ++ct) {
        const int s_base = s_start + ct * 32;
        // stage 32 samples x 2 views: each wave normalizes 4 samples per iter
        #pragma unroll
        for (int it = 0; it < 2; ++it) {
            const int sq = it * 16 + w * 4 + (l >> 4);   // 0..31
            const long off = bb + (long)(s_base + sq) * Kn + c4;
            {
                const float4 q = *(const float4*)(qi + off);
                float4 wv;
                wv.x = q.x * q.x * ici.x; wv.y = q.y * q.y * ici.y;
                wv.z = q.z * q.z * ici.z; wv.w = q.w * q.w * ici.w;
                float rs = wv.x + wv.y + wv.z + wv.w;
                rs += __shfl_xor(rs, 1); rs += __shfl_xor(rs, 2);
                rs += __shfl_xor(rs, 4); rs += __shfl_xor(rs, 8);
                const float ir = 1.f / rs;
                *(float4*)&lpi[sq * 64 + c4] =
                    make_float4(wv.x * ir, wv.y * ir, wv.z * ir, wv.w * ir);
            }
            {
                const float4 q = *(const float4*)(qj + off);
                float4 wv;
                wv.x = q.x * q.x * icj.x; wv.y = q.y * q.y * icj.y;
                wv.z = q.z * q.z * icj.z; wv.w = q.w * q.w * icj.w;
                float rs = wv.x + wv.y + wv.z + wv.w;
                rs += __shfl_xor(rs, 1); rs += __shfl_xor(rs, 2);
                rs += __shfl_xor(rs, 4); rs += __shfl_xor(rs, 8);
                const float ir = 1.f / rs;
                *(float4*)&lpj[sq * 64 + c4] =
                    make_float4(wv.x * ir, wv.y * ir, wv.z * ir, wv.w * ir);
            }
        }
        __syncthreads();

        #pragma unroll 8
        for (int so = 0; so < 32; ++so) {
            const float4 xr = *(const float4*)&lpi[so * 64 + r0];
            const float4 xc = *(const float4*)&lpi[so * 64 + c0];
            const float4 yr = *(const float4*)&lpj[so * 64 + r0];
            const float4 yc = *(const float4*)&lpj[so * 64 + c0];
            const float xra[4] = {xr.x, xr.y, xr.z, xr.w};
            const float xca[4] = {xc.x, xc.y, xc.z, xc.w};
            const float yra[4] = {yr.x, yr.y, yr.z, yr.w};
            const float yca[4] = {yc.x, yc.y, yc.z, yc.w};
            #pragma unroll
            for (int a = 0; a < 4; ++a) {
                #pragma unroll
                for (int c = 0; c < 4; ++c) {
                    aii[a][c] += xra[a] * xca[c];
                    aij[a][c] += xra[a] * yca[c];
                    ajj[a][c] += yra[a] * yca[c];
                }
            }
        }
        __syncthreads();
    }

    float* __restrict__ g = ws + WS_GRAM + b * 3 * 4096;
    #pragma unroll
    for (int a = 0; a < 4; ++a) {
        #pragma unroll
        for (int c = 0; c < 4; ++c) {
            atomicAdd(&g[0 * 4096 + (r0 + a) * 64 + (c0 + c)], aii[a][c]);
            atomicAdd(&g[1 * 4096 + (r0 + a) * 64 + (c0 + c)], aij[a][c]);
            atomicAdd(&g[2 * 4096 + (r0 + a) * 64 + (c0 + c)], ajj[a][c]);
        }
    }
}

// ---------------- Pass 3: per-batch masked-LSE loss ----------------
__device__ __forceinline__ float sim_entry(const float* __restrict__ g, int r, int c) {
    // sim = [[Gii, Gij], [Gij^T, Gjj]]
    if (r < 64) return (c < 64) ? g[r * 64 + c] : g[4096 + r * 64 + (c - 64)];
    return (c < 64) ? g[4096 + c * 64 + (r - 64)] : g[8192 + (r - 64) * 64 + (c - 64)];
}

__global__ __launch_bounds__(128) void k_loss(const float* __restrict__ temp,
                                              float* __restrict__ ws) {
    const int b = blockIdx.x;
    const int r = threadIdx.x;    // row 0..127
    const float* __restrict__ g = ws + WS_GRAM + b * 3 * 4096;
    const float inv_t = 1.f / temp[0];
    const int p = r ^ 64;         // positive-pair column

    float m = -1e30f, pos = 0.f;
    for (int c = 0; c < Nn; ++c) {
        if (c == r) continue;
        const float v = sim_entry(g, r, c) * inv_t;
        m = fmaxf(m, v);
        if (c == p) pos = v;
    }
    float sum = 0.f;
    for (int c = 0; c < Nn; ++c) {
        if (c == r) continue;
        const float v = sim_entry(g, r, c) * inv_t;
        sum += expf(v - m);
    }
    const float val = m + logf(sum) - pos;   // LSE - pos

    __shared__ float red[Nn];
    red[r] = val;
    __syncthreads();
    for (int st = 64; st > 0; st >>= 1) {
        if (r < st) red[r] += red[r + st];
        __syncthreads();
    }
    if (r == 0) ws[WS_LOSS + b] = red[0] / (float)Nn;
}

__global__ void k_final(float* __restrict__ ws, float* __restrict__ out) {
    if (threadIdx.x == 0) {
        float s = 0.f;
        for (int b = 0; b < Bn; ++b) s += ws[WS_LOSS + b];
        out[0] = s / (float)Bn;
    }
}

extern "C" void kernel_launch(void* const* d_in, const int* in_sizes, int n_in,
                              void* d_out, int out_size, void* d_ws, size_t ws_size,
                              hipStream_t stream) {
    const float* qi   = (const float*)d_in[0];
    const float* qj   = (const float*)d_in[1];
    const float* temp = (const float*)d_in[2];
    float* ws  = (float*)d_ws;
    float* out = (float*)d_out;

    // zero the atomically-accumulated gram region every call
    hipMemsetAsync(ws + WS_GRAM, 0, (size_t)Bn * 3 * 4096 * sizeof(float), stream);

    k_colsum<<<Bn * 2 * P1, 256, 0, stream>>>(qi, qj, ws);
    k_colsum_reduce<<<Bn * 2, 64, 0, stream>>>(ws);
    k_gram<<<Bn * NSB, 256, 0, stream>>>(qi, qj, ws);
    k_loss<<<Bn, 128, 0, stream>>>(temp, ws);
    k_final<<<1, 64, 0, stream>>>(ws, out);
}

// Round 2
// 190.229 us; speedup vs baseline: 1.9888x; 1.9888x over previous
//
#include <hip/hip_runtime.h>
#include <math.h>

// Problem constants
#define Bn 32
#define Sn 16384
#define Kn 64
#define Nn 128

#define P1  8            // pass-1 sample-chunks per (b,view)
#define NSB 32           // pass-2 blocks per batch
#define SPB (Sn/NSB)     // 512 samples per gram block
#define NCH (SPB/32)     // 16 K-chunks of 32 samples

typedef __attribute__((ext_vector_type(8))) short bf16x8;   // 8 bf16 (4 VGPR)
typedef __attribute__((ext_vector_type(4))) float f32x4;    // MFMA acc

// workspace layout in floats
#define WS_CSPART 0                          // Bn*2*P1*64
#define WS_CS     (Bn*2*P1*64)               // Bn*2*64
#define WS_GRAM   (WS_CS + Bn*2*64)          // Bn*3*4096 final gram
#define WS_LOSS   (WS_GRAM + Bn*3*4096)      // Bn
#define WS_PART   (WS_LOSS + Bn)             // Bn*NSB*3*4096 partials
#define WS_PART_SZ ((size_t)Bn*NSB*3*4096)

__device__ __forceinline__ unsigned short f2bf(float f) {
    // round-to-nearest-even f32 -> bf16 (values are finite, no NaN handling)
    unsigned int u = __float_as_uint(f);
    u += 0x7FFFu + ((u >> 16) & 1u);
    return (unsigned short)(u >> 16);
}

// ---------------- Pass 1: column sums (deterministic two-stage) ----------------
__global__ __launch_bounds__(256) void k_colsum(const float* __restrict__ qi,
                                                const float* __restrict__ qj,
                                                float* __restrict__ ws) {
    const int blk   = blockIdx.x;       // 0 .. Bn*2*P1-1
    const int chunk = blk % P1;
    const int pair  = blk / P1;         // b*2 + v
    const int v = pair & 1, b = pair >> 1;
    const float* __restrict__ src = v ? qj : qi;
    const int tid = threadIdx.x;
    const int c4 = (tid & 15) * 4;
    const int sg = tid >> 4;
    const long base = (long)b * Sn * Kn + (long)chunk * (Sn / P1) * Kn;

    float4 acc = make_float4(0.f, 0.f, 0.f, 0.f);
    for (int s = sg; s < Sn / P1; s += 16) {
        const float4 q = *(const float4*)(src + base + (long)s * Kn + c4);
        acc.x += q.x; acc.y += q.y; acc.z += q.z; acc.w += q.w;
    }
    __shared__ float red[16 * 64];
    *(float4*)&red[sg * 64 + c4] = acc;
    __syncthreads();
    if (tid < 64) {
        float s = 0.f;
        #pragma unroll
        for (int g = 0; g < 16; ++g) s += red[g * 64 + tid];
        ws[WS_CSPART + (pair * P1 + chunk) * 64 + tid] = s;
    }
}

__global__ void k_colsum_reduce(float* __restrict__ ws) {
    const int pair = blockIdx.x;   // Bn*2 blocks, 64 threads
    const int tid = threadIdx.x;
    float s = 0.f;
    #pragma unroll
    for (int p = 0; p < P1; ++p) s += ws[WS_CSPART + (pair * P1 + p) * 64 + tid];
    ws[WS_CS + pair * 64 + tid] = s;
}

// ---------------- Pass 2: normalize -> bf16 -> MFMA Gram ----------------
// LDS: per view, p^T chunk as [64 cols][40 bf16] (stride 80 B, 32 samples used).
// Frag (mfma_f32_16x16x32_bf16 A and B): lane l holds col = tile*16 + (l&15),
// samples (l>>4)*8 .. +7  ->  one 16B ds_read_b128 per fragment.
template<int ATOMIC>
__global__ __launch_bounds__(256, 4) void k_gram(const float* __restrict__ qi,
                                                 const float* __restrict__ qj,
                                                 float* __restrict__ ws) {
    const int b   = blockIdx.x / NSB;
    const int sb  = blockIdx.x % NSB;
    const int tid = threadIdx.x;
    const int w   = tid >> 6;        // wave 0..3 (owns output rows w*16..+15)
    const int l   = tid & 63;
    const int lc  = tid & 15;        // col-quad / fragment col lane
    const int sp  = tid >> 4;        // sample-pair 0..15
    const int c0  = lc * 4;

    __shared__ unsigned short lp[2][64 * 40];

    const float4 csI = *(const float4*)&ws[WS_CS + (b * 2 + 0) * 64 + c0];
    const float4 csJ = *(const float4*)&ws[WS_CS + (b * 2 + 1) * 64 + c0];
    const float icI[4] = {1.f / csI.x, 1.f / csI.y, 1.f / csI.z, 1.f / csI.w};
    const float icJ[4] = {1.f / csJ.x, 1.f / csJ.y, 1.f / csJ.z, 1.f / csJ.w};

    f32x4 aII[4], aIJ[4], aJJ[4];
    #pragma unroll
    for (int t = 0; t < 4; ++t) {
        aII[t] = (f32x4){0.f, 0.f, 0.f, 0.f};
        aIJ[t] = (f32x4){0.f, 0.f, 0.f, 0.f};
        aJJ[t] = (f32x4){0.f, 0.f, 0.f, 0.f};
    }

    const long bb  = (long)b * Sn * Kn;
    const long s0g = (long)sb * SPB;

    for (int ct = 0; ct < NCH; ++ct) {
        // ---- stage: normalize 32 samples x 64 cols x 2 views into LDS (bf16, transposed) ----
        #pragma unroll
        for (int v = 0; v < 2; ++v) {
            const float* __restrict__ src = v ? qj : qi;
            const float* ic = v ? icJ : icI;
            const long off = bb + (s0g + ct * 32 + 2 * sp) * (long)Kn + c0;
            const float4 qa = *(const float4*)(src + off);
            const float4 qb = *(const float4*)(src + off + Kn);
            float wa[4] = {qa.x * qa.x * ic[0], qa.y * qa.y * ic[1],
                           qa.z * qa.z * ic[2], qa.w * qa.w * ic[3]};
            float wb[4] = {qb.x * qb.x * ic[0], qb.y * qb.y * ic[1],
                           qb.z * qb.z * ic[2], qb.w * qb.w * ic[3]};
            float ra = wa[0] + wa[1] + wa[2] + wa[3];
            float rb = wb[0] + wb[1] + wb[2] + wb[3];
            #pragma unroll
            for (int d = 1; d < 16; d <<= 1) {
                ra += __shfl_xor(ra, d);
                rb += __shfl_xor(rb, d);
            }
            const float ia = 1.f / ra, ib = 1.f / rb;
            #pragma unroll
            for (int cc = 0; cc < 4; ++cc) {
                const unsigned int pk = (unsigned int)f2bf(wa[cc] * ia)
                                      | ((unsigned int)f2bf(wb[cc] * ib) << 16);
                *(unsigned int*)&lp[v][(c0 + cc) * 40 + 2 * sp] = pk;
            }
        }
        __syncthreads();

        // ---- fragments + 12 MFMAs ----
        const int sgo = (l >> 4) * 8;
        bf16x8 fi[4], fj[4];
        #pragma unroll
        for (int t = 0; t < 4; ++t) {
            fi[t] = *(const bf16x8*)&lp[0][(t * 16 + lc) * 40 + sgo];
            fj[t] = *(const bf16x8*)&lp[1][(t * 16 + lc) * 40 + sgo];
        }
        const bf16x8 ai = *(const bf16x8*)&lp[0][(w * 16 + lc) * 40 + sgo];
        const bf16x8 aj = *(const bf16x8*)&lp[1][(w * 16 + lc) * 40 + sgo];
        #pragma unroll
        for (int nt = 0; nt < 4; ++nt) {
            aII[nt] = __builtin_amdgcn_mfma_f32_16x16x32_bf16(ai, fi[nt], aII[nt], 0, 0, 0);
            aIJ[nt] = __builtin_amdgcn_mfma_f32_16x16x32_bf16(ai, fj[nt], aIJ[nt], 0, 0, 0);
            aJJ[nt] = __builtin_amdgcn_mfma_f32_16x16x32_bf16(aj, fj[nt], aJJ[nt], 0, 0, 0);
        }
        __syncthreads();
    }

    // ---- epilogue: C/D layout col = l&15, row = (l>>4)*4 + reg ----
    const int row0 = w * 16 + (l >> 4) * 4;
    if (ATOMIC) {
        float* __restrict__ dst = ws + WS_GRAM + (long)b * 3 * 4096;
        #pragma unroll
        for (int nt = 0; nt < 4; ++nt) {
            #pragma unroll
            for (int r = 0; r < 4; ++r) {
                const int e = (row0 + r) * 64 + nt * 16 + lc;
                atomicAdd(&dst[e],        aII[nt][r]);
                atomicAdd(&dst[4096 + e], aIJ[nt][r]);
                atomicAdd(&dst[8192 + e], aJJ[nt][r]);
            }
        }
    } else {
        float* __restrict__ dst = ws + WS_PART + (long)(b * NSB + sb) * 3 * 4096;
        #pragma unroll
        for (int nt = 0; nt < 4; ++nt) {
            #pragma unroll
            for (int r = 0; r < 4; ++r) {
                const int e = (row0 + r) * 64 + nt * 16 + lc;
                dst[e]        = aII[nt][r];
                dst[4096 + e] = aIJ[nt][r];
                dst[8192 + e] = aJJ[nt][r];
            }
        }
    }
}

// ---------------- Pass 2b: reduce block partials (deterministic) ----------------
__global__ __launch_bounds__(256) void k_gram_reduce(float* __restrict__ ws) {
    const int idx = blockIdx.x * 256 + threadIdx.x;   // < Bn*3*4096
    const int b = idx / (3 * 4096);
    const int e = idx % (3 * 4096);
    float s = 0.f;
    #pragma unroll 8
    for (int p = 0; p < NSB; ++p)
        s += ws[WS_PART + (long)(b * NSB + p) * 3 * 4096 + e];
    ws[WS_GRAM + (long)b * 3 * 4096 + e] = s;
}

// ---------------- Pass 3: per-batch masked-LSE loss ----------------
__device__ __forceinline__ float sim_entry(const float* __restrict__ g, int r, int c) {
    // sim = [[Gii, Gij], [Gij^T, Gjj]]
    if (r < 64) return (c < 64) ? g[r * 64 + c] : g[4096 + r * 64 + (c - 64)];
    return (c < 64) ? g[4096 + c * 64 + (r - 64)] : g[8192 + (r - 64) * 64 + (c - 64)];
}

__global__ __launch_bounds__(128) void k_loss(const float* __restrict__ temp,
                                              float* __restrict__ ws) {
    const int b = blockIdx.x;
    const int r = threadIdx.x;    // row 0..127
    const float* __restrict__ g = ws + WS_GRAM + (long)b * 3 * 4096;
    const float inv_t = 1.f / temp[0];
    const int p = r ^ 64;         // positive-pair column

    float m = -1e30f, pos = 0.f;
    for (int c = 0; c < Nn; ++c) {
        if (c == r) continue;
        const float v = sim_entry(g, r, c) * inv_t;
        m = fmaxf(m, v);
        if (c == p) pos = v;
    }
    float sum = 0.f;
    for (int c = 0; c < Nn; ++c) {
        if (c == r) continue;
        const float v = sim_entry(g, r, c) * inv_t;
        sum += expf(v - m);
    }
    const float val = m + logf(sum) - pos;   // LSE - pos

    __shared__ float red[Nn];
    red[r] = val;
    __syncthreads();
    for (int st = 64; st > 0; st >>= 1) {
        if (r < st) red[r] += red[r + st];
        __syncthreads();
    }
    if (r == 0) ws[WS_LOSS + b] = red[0] / (float)Nn;
}

__global__ void k_final(float* __restrict__ ws, float* __restrict__ out) {
    if (threadIdx.x == 0) {
        float s = 0.f;
        for (int b = 0; b < Bn; ++b) s += ws[WS_LOSS + b];
        out[0] = s / (float)Bn;
    }
}

extern "C" void kernel_launch(void* const* d_in, const int* in_sizes, int n_in,
                              void* d_out, int out_size, void* d_ws, size_t ws_size,
                              hipStream_t stream) {
    const float* qi   = (const float*)d_in[0];
    const float* qj   = (const float*)d_in[1];
    const float* temp = (const float*)d_in[2];
    float* ws  = (float*)d_ws;
    float* out = (float*)d_out;

    const size_t need_f = (size_t)WS_PART + WS_PART_SZ;
    const bool partial = ws_size >= need_f * sizeof(float);

    k_colsum<<<Bn * 2 * P1, 256, 0, stream>>>(qi, qj, ws);
    k_colsum_reduce<<<Bn * 2, 64, 0, stream>>>(ws);

    if (partial) {
        k_gram<0><<<Bn * NSB, 256, 0, stream>>>(qi, qj, ws);
        k_gram_reduce<<<(Bn * 3 * 4096) / 256, 256, 0, stream>>>(ws);
    } else {
        hipMemsetAsync(ws + WS_GRAM, 0, (size_t)Bn * 3 * 4096 * sizeof(float), stream);
        k_gram<1><<<Bn * NSB, 256, 0, stream>>>(qi, qj, ws);
    }

    k_loss<<<Bn, 128, 0, stream>>>(temp, ws);
    k_final<<<1, 64, 0, stream>>>(ws, out);
}

// Round 3
// 166.076 us; speedup vs baseline: 2.2780x; 1.1454x over previous
//
#include <hip/hip_runtime.h>
#include <math.h>

// Problem constants
#define Bn 32
#define Sn 16384
#define Kn 64
#define Nn 128

#define P1  32           // pass-1 sample-chunks per (b,view)  (2048 blocks)
#define NSB 32           // pass-2 blocks per batch
#define SPB (Sn/NSB)     // 512 samples per gram block
#define NCH (SPB/32)     // 16 K-chunks of 32 samples

typedef __attribute__((ext_vector_type(8))) short bf16x8;   // 8 bf16 (4 VGPR)
typedef __attribute__((ext_vector_type(4))) float f32x4;    // MFMA acc

// workspace layout in floats
#define WS_CSPART 0                          // Bn*2*P1*64
#define WS_CS     (Bn*2*P1*64)               // Bn*2*64
#define WS_GRAM   (WS_CS + Bn*2*64)          // Bn*3*4096 final gram
#define WS_LOSS   (WS_GRAM + Bn*3*4096)      // Bn
#define WS_PART   (WS_LOSS + Bn)             // Bn*NSB*3*4096 partials
#define WS_PART_SZ ((size_t)Bn*NSB*3*4096)

__device__ __forceinline__ unsigned short f2bf(float f) {
    // round-to-nearest-even f32 -> bf16 (values are finite, no NaN handling)
    unsigned int u = __float_as_uint(f);
    u += 0x7FFFu + ((u >> 16) & 1u);
    return (unsigned short)(u >> 16);
}

// ---------------- Pass 1: column sums (deterministic two-stage) ----------------
// 2048 blocks (8/CU, full occupancy), 8 independent float4 loads in flight/thread.
__global__ __launch_bounds__(256) void k_colsum(const float* __restrict__ qi,
                                                const float* __restrict__ qj,
                                                float* __restrict__ ws) {
    const int blk   = blockIdx.x;       // 0 .. Bn*2*P1-1
    const int chunk = blk % P1;
    const int pair  = blk / P1;         // b*2 + v
    const int v = pair & 1, b = pair >> 1;
    const float* __restrict__ src = v ? qj : qi;
    const int tid = threadIdx.x;
    const int c4 = (tid & 15) * 4;
    const int sg = tid >> 4;            // 0..15
    const long base = (long)b * Sn * Kn + (long)chunk * (Sn / P1) * Kn;
    const float* __restrict__ p0 = src + base + (long)sg * Kn + c4;

    float4 acc = make_float4(0.f, 0.f, 0.f, 0.f);
    #pragma unroll 8
    for (int s = 0; s < (Sn / P1) / 16; ++s) {   // 32 iters, rows sg + 16*s
        const float4 q = *(const float4*)(p0 + (long)s * 16 * Kn);
        acc.x += q.x; acc.y += q.y; acc.z += q.z; acc.w += q.w;
    }
    __shared__ float red[16 * 64];
    *(float4*)&red[sg * 64 + c4] = acc;
    __syncthreads();
    if (tid < 64) {
        float s = 0.f;
        #pragma unroll
        for (int g = 0; g < 16; ++g) s += red[g * 64 + tid];
        ws[WS_CSPART + (pair * P1 + chunk) * 64 + tid] = s;
    }
}

__global__ void k_colsum_reduce(float* __restrict__ ws) {
    const int pair = blockIdx.x;   // Bn*2 blocks, 64 threads
    const int tid = threadIdx.x;
    float s = 0.f;
    #pragma unroll
    for (int p = 0; p < P1; ++p) s += ws[WS_CSPART + (pair * P1 + p) * 64 + tid];
    ws[WS_CS + pair * 64 + tid] = s;
}

// ---------------- Pass 2: normalize -> bf16 -> MFMA Gram (pipelined) ----------------
// LDS: [buf][view] p^T chunk as [64 cols][40 bf16] (stride 80 B, 32 samples used).
// Frag (mfma_f32_16x16x32_bf16 A and B): lane l holds col = tile*16 + (l&15),
// samples (l>>4)*8 .. +7  ->  one 16B ds_read_b128 per fragment.
// Pipeline: issue chunk ct+2 loads early; MFMA on buf[cur]; normalize+write buf[nxt].
template<int ATOMIC>
__global__ __launch_bounds__(256, 4) void k_gram(const float* __restrict__ qi,
                                                 const float* __restrict__ qj,
                                                 float* __restrict__ ws) {
    const int b   = blockIdx.x / NSB;
    const int sb  = blockIdx.x % NSB;
    const int tid = threadIdx.x;
    const int w   = tid >> 6;        // wave 0..3 (owns output rows w*16..+15)
    const int l   = tid & 63;
    const int lc  = tid & 15;        // fragment col lane
    const int sp  = tid >> 4;        // sample-pair 0..15
    const int c0  = lc * 4;

    __shared__ unsigned short lp[2][2][64 * 40];   // [buf][view], 20.5 KB

    const float4 csI = *(const float4*)&ws[WS_CS + (b * 2 + 0) * 64 + c0];
    const float4 csJ = *(const float4*)&ws[WS_CS + (b * 2 + 1) * 64 + c0];
    const float icI[4] = {1.f / csI.x, 1.f / csI.y, 1.f / csI.z, 1.f / csI.w};
    const float icJ[4] = {1.f / csJ.x, 1.f / csJ.y, 1.f / csJ.z, 1.f / csJ.w};

    f32x4 aII[4], aIJ[4], aJJ[4];
    #pragma unroll
    for (int t = 0; t < 4; ++t) {
        aII[t] = (f32x4){0.f, 0.f, 0.f, 0.f};
        aIJ[t] = (f32x4){0.f, 0.f, 0.f, 0.f};
        aJJ[t] = (f32x4){0.f, 0.f, 0.f, 0.f};
    }

    const long bb  = (long)b * Sn * Kn;
    const long s0g = (long)sb * SPB;

    float4 pfa[2], pfb[2];   // prefetched chunk: [view] rows 2sp, 2sp+1

    auto issue = [&](int ct) {
        const long off = bb + (s0g + ct * 32 + 2 * sp) * (long)Kn + c0;
        pfa[0] = *(const float4*)(qi + off);
        pfb[0] = *(const float4*)(qi + off + Kn);
        pfa[1] = *(const float4*)(qj + off);
        pfb[1] = *(const float4*)(qj + off + Kn);
    };
    auto stage = [&](int buf) {
        #pragma unroll
        for (int v = 0; v < 2; ++v) {
            const float* ic = v ? icJ : icI;
            const float4 qa = pfa[v], qb = pfb[v];
            float wa[4] = {qa.x * qa.x * ic[0], qa.y * qa.y * ic[1],
                           qa.z * qa.z * ic[2], qa.w * qa.w * ic[3]};
            float wb[4] = {qb.x * qb.x * ic[0], qb.y * qb.y * ic[1],
                           qb.z * qb.z * ic[2], qb.w * qb.w * ic[3]};
            float ra = wa[0] + wa[1] + wa[2] + wa[3];
            float rb = wb[0] + wb[1] + wb[2] + wb[3];
            #pragma unroll
            for (int d = 1; d < 16; d <<= 1) {
                ra += __shfl_xor(ra, d);
                rb += __shfl_xor(rb, d);
            }
            const float ia = 1.f / ra, ib = 1.f / rb;
            #pragma unroll
            for (int cc = 0; cc < 4; ++cc) {
                const unsigned int pk = (unsigned int)f2bf(wa[cc] * ia)
                                      | ((unsigned int)f2bf(wb[cc] * ib) << 16);
                *(unsigned int*)&lp[buf][v][(c0 + cc) * 40 + 2 * sp] = pk;
            }
        }
    };

    // prologue
    issue(0);
    stage(0);
    issue(1);
    __syncthreads();

    const int sgo = (l >> 4) * 8;
    for (int ct = 0; ct < NCH; ++ct) {
        const int cur = ct & 1;
        // A-frags for this wave's row tile
        const bf16x8 ai = *(const bf16x8*)&lp[cur][0][(w * 16 + lc) * 40 + sgo];
        const bf16x8 aj = *(const bf16x8*)&lp[cur][1][(w * 16 + lc) * 40 + sgo];
        #pragma unroll
        for (int nt = 0; nt < 4; ++nt) {
            const bf16x8 fi = *(const bf16x8*)&lp[cur][0][(nt * 16 + lc) * 40 + sgo];
            const bf16x8 fj = *(const bf16x8*)&lp[cur][1][(nt * 16 + lc) * 40 + sgo];
            aII[nt] = __builtin_amdgcn_mfma_f32_16x16x32_bf16(ai, fi, aII[nt], 0, 0, 0);
            aIJ[nt] = __builtin_amdgcn_mfma_f32_16x16x32_bf16(ai, fj, aIJ[nt], 0, 0, 0);
            aJJ[nt] = __builtin_amdgcn_mfma_f32_16x16x32_bf16(aj, fj, aJJ[nt], 0, 0, 0);
        }
        if (ct + 1 < NCH) {
            stage(cur ^ 1);                       // vmem-waits chunk ct+1, writes other buf
            if (ct + 2 < NCH) issue(ct + 2);      // next loads in flight during next MFMA
        }
        __syncthreads();
    }

    // ---- epilogue: C/D layout col = l&15, row = (l>>4)*4 + reg ----
    const int row0 = w * 16 + (l >> 4) * 4;
    if (ATOMIC) {
        float* __restrict__ dst = ws + WS_GRAM + (long)b * 3 * 4096;
        #pragma unroll
        for (int nt = 0; nt < 4; ++nt) {
            #pragma unroll
            for (int r = 0; r < 4; ++r) {
                const int e = (row0 + r) * 64 + nt * 16 + lc;
                atomicAdd(&dst[e],        aII[nt][r]);
                atomicAdd(&dst[4096 + e], aIJ[nt][r]);
                atomicAdd(&dst[8192 + e], aJJ[nt][r]);
            }
        }
    } else {
        float* __restrict__ dst = ws + WS_PART + (long)(b * NSB + sb) * 3 * 4096;
        #pragma unroll
        for (int nt = 0; nt < 4; ++nt) {
            #pragma unroll
            for (int r = 0; r < 4; ++r) {
                const int e = (row0 + r) * 64 + nt * 16 + lc;
                dst[e]        = aII[nt][r];
                dst[4096 + e] = aIJ[nt][r];
                dst[8192 + e] = aJJ[nt][r];
            }
        }
    }
}

// ---------------- Pass 2b: reduce block partials (deterministic) ----------------
__global__ __launch_bounds__(256) void k_gram_reduce(float* __restrict__ ws) {
    const int idx = blockIdx.x * 256 + threadIdx.x;   // < Bn*3*4096
    const int b = idx / (3 * 4096);
    const int e = idx % (3 * 4096);
    float s = 0.f;
    #pragma unroll 8
    for (int p = 0; p < NSB; ++p)
        s += ws[WS_PART + (long)(b * NSB + p) * 3 * 4096 + e];
    ws[WS_GRAM + (long)b * 3 * 4096 + e] = s;
}

// ---------------- Pass 3: per-batch masked-LSE loss ----------------
__device__ __forceinline__ float sim_entry(const float* __restrict__ g, int r, int c) {
    // sim = [[Gii, Gij], [Gij^T, Gjj]]
    if (r < 64) return (c < 64) ? g[r * 64 + c] : g[4096 + r * 64 + (c - 64)];
    return (c < 64) ? g[4096 + c * 64 + (r - 64)] : g[8192 + (r - 64) * 64 + (c - 64)];
}

__global__ __launch_bounds__(128) void k_loss(const float* __restrict__ temp,
                                              float* __restrict__ ws) {
    const int b = blockIdx.x;
    const int r = threadIdx.x;    // row 0..127
    const float* __restrict__ g = ws + WS_GRAM + (long)b * 3 * 4096;
    const float inv_t = 1.f / temp[0];
    const int p = r ^ 64;         // positive-pair column

    float m = -1e30f, pos = 0.f;
    for (int c = 0; c < Nn; ++c) {
        if (c == r) continue;
        const float v = sim_entry(g, r, c) * inv_t;
        m = fmaxf(m, v);
        if (c == p) pos = v;
    }
    float sum = 0.f;
    for (int c = 0; c < Nn; ++c) {
        if (c == r) continue;
        const float v = sim_entry(g, r, c) * inv_t;
        sum += expf(v - m);
    }
    const float val = m + logf(sum) - pos;   // LSE - pos

    __shared__ float red[Nn];
    red[r] = val;
    __syncthreads();
    for (int st = 64; st > 0; st >>= 1) {
        if (r < st) red[r] += red[r + st];
        __syncthreads();
    }
    if (r == 0) ws[WS_LOSS + b] = red[0] / (float)Nn;
}

__global__ void k_final(float* __restrict__ ws, float* __restrict__ out) {
    if (threadIdx.x == 0) {
        float s = 0.f;
        for (int b = 0; b < Bn; ++b) s += ws[WS_LOSS + b];
        out[0] = s / (float)Bn;
    }
}

extern "C" void kernel_launch(void* const* d_in, const int* in_sizes, int n_in,
                              void* d_out, int out_size, void* d_ws, size_t ws_size,
                              hipStream_t stream) {
    const float* qi   = (const float*)d_in[0];
    const float* qj   = (const float*)d_in[1];
    const float* temp = (const float*)d_in[2];
    float* ws  = (float*)d_ws;
    float* out = (float*)d_out;

    const size_t need_f = (size_t)WS_PART + WS_PART_SZ;
    const bool partial = ws_size >= need_f * sizeof(float);

    k_colsum<<<Bn * 2 * P1, 256, 0, stream>>>(qi, qj, ws);
    k_colsum_reduce<<<Bn * 2, 64, 0, stream>>>(ws);

    if (partial) {
        k_gram<0><<<Bn * NSB, 256, 0, stream>>>(qi, qj, ws);
        k_gram_reduce<<<(Bn * 3 * 4096) / 256, 256, 0, stream>>>(ws);
    } else {
        hipMemsetAsync(ws + WS_GRAM, 0, (size_t)Bn * 3 * 4096 * sizeof(float), stream);
        k_gram<1><<<Bn * NSB, 256, 0, stream>>>(qi, qj, ws);
    }

    k_loss<<<Bn, 128, 0, stream>>>(temp, ws);
    k_final<<<1, 64, 0, stream>>>(ws, out);
}

// Round 4
// 163.360 us; speedup vs baseline: 2.3159x; 1.0166x over previous
//
#include <hip/hip_runtime.h>
#include <math.h>

// Problem constants
#define Bn 32
#define Sn 16384
#define Kn 64
#define Nn 128

#define P1  16           // pass-1 sample-chunks per (b,view)  (1024 blocks, 4/CU)
#define NSB 32           // pass-2 blocks per batch
#define SPB (Sn/NSB)     // 512 samples per gram block
#define NCH (SPB/32)     // 16 K-chunks of 32 samples

typedef __attribute__((ext_vector_type(8))) short bf16x8;   // 8 bf16 (4 VGPR)
typedef __attribute__((ext_vector_type(4))) float f32x4;    // MFMA acc

// workspace layout in floats
#define WS_CSPART 0                          // Bn*2*P1*64 = 65536
#define WS_GRAM   (Bn*2*P1*64)               // Bn*3*4096 final gram
#define WS_LOSS   (WS_GRAM + Bn*3*4096)      // Bn
#define WS_PART   (WS_LOSS + Bn)             // Bn*NSB*3*4096 partials
#define WS_PART_SZ ((size_t)Bn*NSB*3*4096)

__device__ __forceinline__ unsigned short f2bf(float f) {
    // round-to-nearest-even f32 -> bf16 (values are finite, no NaN handling)
    unsigned int u = __float_as_uint(f);
    u += 0x7FFFu + ((u >> 16) & 1u);
    return (unsigned short)(u >> 16);
}

// ---------------- Pass 1: column-sum partials ----------------
// 1024 blocks; each thread keeps 16 float4 loads in flight (explicit v[16]
// array forces 64 live VGPRs -> no destination-reuse serialization).
__global__ __launch_bounds__(256) void k_colsum(const float* __restrict__ qi,
                                                const float* __restrict__ qj,
                                                float* __restrict__ ws) {
    const int blk   = blockIdx.x;       // 0 .. Bn*2*P1-1
    const int chunk = blk % P1;
    const int pair  = blk / P1;         // b*2 + v
    const int v = pair & 1, b = pair >> 1;
    const float* __restrict__ src = v ? qj : qi;
    const int tid = threadIdx.x;
    const int c4 = (tid & 15) * 4;
    const int sg = tid >> 4;            // 0..15
    const long base = (long)b * Sn * Kn + (long)chunk * (Sn / P1) * Kn;
    const float* __restrict__ p0 = src + base + (long)sg * Kn + c4;

    float4 acc = make_float4(0.f, 0.f, 0.f, 0.f);
    // (Sn/P1)/16 = 64 rows per thread, in 4 groups of 16 in-flight loads
    #pragma unroll 1
    for (int g = 0; g < 4; ++g) {
        float4 vv[16];
        #pragma unroll
        for (int u = 0; u < 16; ++u)
            vv[u] = *(const float4*)(p0 + (long)(g * 16 + u) * 16 * Kn);
        #pragma unroll
        for (int u = 0; u < 16; ++u) {
            acc.x += vv[u].x; acc.y += vv[u].y;
            acc.z += vv[u].z; acc.w += vv[u].w;
        }
    }
    __shared__ float red[16 * 64];
    *(float4*)&red[sg * 64 + c4] = acc;
    __syncthreads();
    if (tid < 64) {
        float s = 0.f;
        #pragma unroll
        for (int g = 0; g < 16; ++g) s += red[g * 64 + tid];
        ws[WS_CSPART + (pair * P1 + chunk) * 64 + tid] = s;
    }
}

// ---------------- Pass 2: normalize -> bf16 -> MFMA Gram (pipelined) ----------------
// Prologue folds the colsum-partial reduction (was a separate kernel).
// LDS: [buf][view] p^T chunk as [64 cols][40 bf16] (stride 80 B, 32 samples used).
// Frag (mfma_f32_16x16x32_bf16 A and B): lane l holds col = tile*16 + (l&15),
// samples (l>>4)*8 .. +7  ->  one 16B ds_read_b128 per fragment.
template<int ATOMIC>
__global__ __launch_bounds__(256, 4) void k_gram(const float* __restrict__ qi,
                                                 const float* __restrict__ qj,
                                                 float* __restrict__ ws) {
    const int b   = blockIdx.x / NSB;
    const int sb  = blockIdx.x % NSB;
    const int tid = threadIdx.x;
    const int w   = tid >> 6;        // wave 0..3 (owns output rows w*16..+15)
    const int l   = tid & 63;
    const int lc  = tid & 15;        // fragment col lane
    const int sp  = tid >> 4;        // sample-pair 0..15
    const int c0  = lc * 4;

    __shared__ unsigned short lp[2][2][64 * 40];   // [buf][view], 20.5 KB
    __shared__ float csh[128];                     // colsums: [view][64]

    // ---- fold: reduce colsum partials for this batch ----
    if (tid < 128) {
        const int view = tid >> 6, col = tid & 63;
        float s = 0.f;
        #pragma unroll
        for (int p = 0; p < P1; ++p)
            s += ws[WS_CSPART + ((b * 2 + view) * P1 + p) * 64 + col];
        csh[view * 64 + col] = s;
    }
    __syncthreads();

    const float icI[4] = {1.f / csh[c0], 1.f / csh[c0 + 1],
                          1.f / csh[c0 + 2], 1.f / csh[c0 + 3]};
    const float icJ[4] = {1.f / csh[64 + c0], 1.f / csh[64 + c0 + 1],
                          1.f / csh[64 + c0 + 2], 1.f / csh[64 + c0 + 3]};

    f32x4 aII[4], aIJ[4], aJJ[4];
    #pragma unroll
    for (int t = 0; t < 4; ++t) {
        aII[t] = (f32x4){0.f, 0.f, 0.f, 0.f};
        aIJ[t] = (f32x4){0.f, 0.f, 0.f, 0.f};
        aJJ[t] = (f32x4){0.f, 0.f, 0.f, 0.f};
    }

    const long bb  = (long)b * Sn * Kn;
    const long s0g = (long)sb * SPB;

    float4 pfa[2], pfb[2];   // prefetched chunk: [view] rows 2sp, 2sp+1

    auto issue = [&](int ct) {
        const long off = bb + (s0g + ct * 32 + 2 * sp) * (long)Kn + c0;
        pfa[0] = *(const float4*)(qi + off);
        pfb[0] = *(const float4*)(qi + off + Kn);
        pfa[1] = *(const float4*)(qj + off);
        pfb[1] = *(const float4*)(qj + off + Kn);
    };
    auto stage = [&](int buf) {
        #pragma unroll
        for (int v = 0; v < 2; ++v) {
            const float* ic = v ? icJ : icI;
            const float4 qa = pfa[v], qb = pfb[v];
            float wa[4] = {qa.x * qa.x * ic[0], qa.y * qa.y * ic[1],
                           qa.z * qa.z * ic[2], qa.w * qa.w * ic[3]};
            float wb[4] = {qb.x * qb.x * ic[0], qb.y * qb.y * ic[1],
                           qb.z * qb.z * ic[2], qb.w * qb.w * ic[3]};
            float ra = wa[0] + wa[1] + wa[2] + wa[3];
            float rb = wb[0] + wb[1] + wb[2] + wb[3];
            #pragma unroll
            for (int d = 1; d < 16; d <<= 1) {
                ra += __shfl_xor(ra, d);
                rb += __shfl_xor(rb, d);
            }
            const float ia = 1.f / ra, ib = 1.f / rb;
            #pragma unroll
            for (int cc = 0; cc < 4; ++cc) {
                const unsigned int pk = (unsigned int)f2bf(wa[cc] * ia)
                                      | ((unsigned int)f2bf(wb[cc] * ib) << 16);
                *(unsigned int*)&lp[buf][v][(c0 + cc) * 40 + 2 * sp] = pk;
            }
        }
    };

    // prologue
    issue(0);
    stage(0);
    issue(1);
    __syncthreads();

    const int sgo = (l >> 4) * 8;
    for (int ct = 0; ct < NCH; ++ct) {
        const int cur = ct & 1;
        const bf16x8 ai = *(const bf16x8*)&lp[cur][0][(w * 16 + lc) * 40 + sgo];
        const bf16x8 aj = *(const bf16x8*)&lp[cur][1][(w * 16 + lc) * 40 + sgo];
        #pragma unroll
        for (int nt = 0; nt < 4; ++nt) {
            const bf16x8 fi = *(const bf16x8*)&lp[cur][0][(nt * 16 + lc) * 40 + sgo];
            const bf16x8 fj = *(const bf16x8*)&lp[cur][1][(nt * 16 + lc) * 40 + sgo];
            aII[nt] = __builtin_amdgcn_mfma_f32_16x16x32_bf16(ai, fi, aII[nt], 0, 0, 0);
            aIJ[nt] = __builtin_amdgcn_mfma_f32_16x16x32_bf16(ai, fj, aIJ[nt], 0, 0, 0);
            aJJ[nt] = __builtin_amdgcn_mfma_f32_16x16x32_bf16(aj, fj, aJJ[nt], 0, 0, 0);
        }
        if (ct + 1 < NCH) {
            stage(cur ^ 1);                       // waits chunk ct+1 loads, fills other buf
            if (ct + 2 < NCH) issue(ct + 2);      // in flight across sync + next MFMA
        }
        __syncthreads();
    }

    // ---- epilogue: C/D layout col = l&15, row = (l>>4)*4 + reg ----
    const int row0 = w * 16 + (l >> 4) * 4;
    if (ATOMIC) {
        float* __restrict__ dst = ws + WS_GRAM + (long)b * 3 * 4096;
        #pragma unroll
        for (int nt = 0; nt < 4; ++nt) {
            #pragma unroll
            for (int r = 0; r < 4; ++r) {
                const int e = (row0 + r) * 64 + nt * 16 + lc;
                atomicAdd(&dst[e],        aII[nt][r]);
                atomicAdd(&dst[4096 + e], aIJ[nt][r]);
                atomicAdd(&dst[8192 + e], aJJ[nt][r]);
            }
        }
    } else {
        float* __restrict__ dst = ws + WS_PART + (long)(b * NSB + sb) * 3 * 4096;
        #pragma unroll
        for (int nt = 0; nt < 4; ++nt) {
            #pragma unroll
            for (int r = 0; r < 4; ++r) {
                const int e = (row0 + r) * 64 + nt * 16 + lc;
                dst[e]        = aII[nt][r];
                dst[4096 + e] = aIJ[nt][r];
                dst[8192 + e] = aJJ[nt][r];
            }
        }
    }
}

// ---------------- Pass 2b: reduce block partials (deterministic) ----------------
__global__ __launch_bounds__(256) void k_gram_reduce(float* __restrict__ ws) {
    const int idx = blockIdx.x * 256 + threadIdx.x;   // < Bn*3*4096
    const int b = idx / (3 * 4096);
    const int e = idx % (3 * 4096);
    float s = 0.f;
    #pragma unroll 8
    for (int p = 0; p < NSB; ++p)
        s += ws[WS_PART + (long)(b * NSB + p) * 3 * 4096 + e];
    ws[WS_GRAM + (long)b * 3 * 4096 + e] = s;
}

// ---------------- Pass 3: per-batch masked-LSE loss ----------------
__device__ __forceinline__ float sim_entry(const float* __restrict__ g, int r, int c) {
    // sim = [[Gii, Gij], [Gij^T, Gjj]]
    if (r < 64) return (c < 64) ? g[r * 64 + c] : g[4096 + r * 64 + (c - 64)];
    return (c < 64) ? g[4096 + c * 64 + (r - 64)] : g[8192 + (r - 64) * 64 + (c - 64)];
}

__global__ __launch_bounds__(128) void k_loss(const float* __restrict__ temp,
                                              float* __restrict__ ws) {
    const int b = blockIdx.x;
    const int r = threadIdx.x;    // row 0..127
    const float* __restrict__ g = ws + WS_GRAM + (long)b * 3 * 4096;
    const float inv_t = 1.f / temp[0];
    const int p = r ^ 64;         // positive-pair column

    float m = -1e30f, pos = 0.f;
    for (int c = 0; c < Nn; ++c) {
        if (c == r) continue;
        const float v = sim_entry(g, r, c) * inv_t;
        m = fmaxf(m, v);
        if (c == p) pos = v;
    }
    float sum = 0.f;
    for (int c = 0; c < Nn; ++c) {
        if (c == r) continue;
        const float v = sim_entry(g, r, c) * inv_t;
        sum += expf(v - m);
    }
    const float val = m + logf(sum) - pos;   // LSE - pos

    __shared__ float red[Nn];
    red[r] = val;
    __syncthreads();
    for (int st = 64; st > 0; st >>= 1) {
        if (r < st) red[r] += red[r + st];
        __syncthreads();
    }
    if (r == 0) ws[WS_LOSS + b] = red[0] / (float)Nn;
}

__global__ void k_final(float* __restrict__ ws, float* __restrict__ out) {
    if (threadIdx.x == 0) {
        float s = 0.f;
        for (int b = 0; b < Bn; ++b) s += ws[WS_LOSS + b];
        out[0] = s / (float)Bn;
    }
}

extern "C" void kernel_launch(void* const* d_in, const int* in_sizes, int n_in,
                              void* d_out, int out_size, void* d_ws, size_t ws_size,
                              hipStream_t stream) {
    const float* qi   = (const float*)d_in[0];
    const float* qj   = (const float*)d_in[1];
    const float* temp = (const float*)d_in[2];
    float* ws  = (float*)d_ws;
    float* out = (float*)d_out;

    const size_t need_f = (size_t)WS_PART + WS_PART_SZ;
    const bool partial = ws_size >= need_f * sizeof(float);

    k_colsum<<<Bn * 2 * P1, 256, 0, stream>>>(qi, qj, ws);

    if (partial) {
        k_gram<0><<<Bn * NSB, 256, 0, stream>>>(qi, qj, ws);
        k_gram_reduce<<<(Bn * 3 * 4096) / 256, 256, 0, stream>>>(ws);
    } else {
        hipMemsetAsync(ws + WS_GRAM, 0, (size_t)Bn * 3 * 4096 * sizeof(float), stream);
        k_gram<1><<<Bn * NSB, 256, 0, stream>>>(qi, qj, ws);
    }

    k_loss<<<Bn, 128, 0, stream>>>(temp, ws);
    k_final<<<1, 64, 0, stream>>>(ws, out);
}